// Round 1
// baseline (1505.516 us; speedup 1.0000x reference)
//
#include <hip/hip_runtime.h>
#include <hip/hip_bf16.h>

#define NQ 10000
#define BS 6
#define NV 30825   // 23200 + 5800 + 1450 + 375

// ---------------------------------------------------------------------------
// Generic fused GEMM + bias: C[M,N] = A[M,256] @ W[256,N] + bias[N]
// Block: 256 threads, each owns one output column n = blockIdx.y*256 + tid
// and BM=16 rows. A tile staged in LDS (broadcast reads), W loads coalesced.
// ---------------------------------------------------------------------------
template <bool BF16OUT>
__global__ __launch_bounds__(256) void gemm_kernel(
    const float* __restrict__ A, const float* __restrict__ W,
    const float* __restrict__ bias, void* __restrict__ C, int M, int N) {
  __shared__ float As[16 * 256];
  const int tid = threadIdx.x;
  const int m0 = blockIdx.x * 16;
  const int n = blockIdx.y * 256 + tid;

#pragma unroll
  for (int j = 0; j < 16; ++j) {
    int m = m0 + j;
    As[j * 256 + tid] = (m < M) ? A[(size_t)m * 256 + tid] : 0.f;
  }
  __syncthreads();

  float acc[16];
#pragma unroll
  for (int i = 0; i < 16; ++i) acc[i] = 0.f;

  for (int k = 0; k < 256; k += 4) {
    float w0 = W[(size_t)(k + 0) * N + n];
    float w1 = W[(size_t)(k + 1) * N + n];
    float w2 = W[(size_t)(k + 2) * N + n];
    float w3 = W[(size_t)(k + 3) * N + n];
#pragma unroll
    for (int i = 0; i < 16; ++i) {
      float a0 = As[i * 256 + k + 0];
      float a1 = As[i * 256 + k + 1];
      float a2 = As[i * 256 + k + 2];
      float a3 = As[i * 256 + k + 3];
      acc[i] = fmaf(a0, w0, acc[i]);
      acc[i] = fmaf(a1, w1, acc[i]);
      acc[i] = fmaf(a2, w2, acc[i]);
      acc[i] = fmaf(a3, w3, acc[i]);
    }
  }

  float bv = bias[n];
#pragma unroll
  for (int i = 0; i < 16; ++i) {
    int m = m0 + i;
    if (m < M) {
      float r = acc[i] + bv;
      if (BF16OUT)
        ((__hip_bfloat16*)C)[(size_t)m * N + n] = __float2bfloat16(r);
      else
        ((float*)C)[(size_t)m * N + n] = r;
    }
  }
}

// ---------------------------------------------------------------------------
// Sampling kernel: one block per (b, q). 256 threads = 8 heads x 32 head-dim.
// Softmax over 32 (level,point) logits per head via 32-lane shfl reduction.
// ---------------------------------------------------------------------------
__global__ __launch_bounds__(256) void msda_sample_kernel(
    const __hip_bfloat16* __restrict__ vproj,  // [BS, NV, 8, 32] bf16
    const float* __restrict__ off,             // [BS*NQ, 512]
    const float* __restrict__ attn,            // [BS*NQ, 256]
    const float* __restrict__ ref,             // [BS*NQ, 4, 2]
    float* __restrict__ out) {                 // [BS*NQ, 256]
  const int bq = blockIdx.x;
  const int tid = threadIdx.x;
  const int h = tid >> 5;
  const int c = tid & 31;
  const int b = bq / NQ;

  __shared__ float s_off[512];
  __shared__ float s_attn[256];

  s_off[tid] = off[(size_t)bq * 512 + tid];
  s_off[tid + 256] = off[(size_t)bq * 512 + 256 + tid];

  // softmax over groups of 32 lanes (one head per half-wave group)
  float logit = attn[(size_t)bq * 256 + tid];
  float mx = logit;
#pragma unroll
  for (int m = 16; m >= 1; m >>= 1) mx = fmaxf(mx, __shfl_xor(mx, m, 32));
  float e = __expf(logit - mx);
  float s = e;
#pragma unroll
  for (int m = 16; m >= 1; m >>= 1) s += __shfl_xor(s, m, 32);
  s_attn[tid] = e / s;
  __syncthreads();

  float rx[4], ry[4];
#pragma unroll
  for (int z = 0; z < 4; ++z) {
    rx[z] = ref[(size_t)bq * 8 + z * 2 + 0];
    ry[z] = ref[(size_t)bq * 8 + z * 2 + 1];
  }

  const __hip_bfloat16* vb = vproj + (size_t)b * NV * 256 + h * 32 + c;
  float acc = 0.f;

  constexpr int LH[4] = {116, 58, 29, 15};
  constexpr int LW[4] = {200, 100, 50, 25};
  constexpr int LS[4] = {0, 23200, 29000, 30450};

#pragma unroll
  for (int l = 0; l < 4; ++l) {
    const int H = LH[l], W = LW[l];
    const __hip_bfloat16* vl = vb + (size_t)LS[l] * 256;
#pragma unroll
    for (int p = 0; p < 8; ++p) {
      const int z = p & 3;
      float ox = s_off[((h * 4 + l) * 8 + p) * 2 + 0];
      float oy = s_off[((h * 4 + l) * 8 + p) * 2 + 1];
      // loc = ref + off/ (W,H); x = loc_x*W - 0.5 = ref_x*W + off_x - 0.5
      float x = rx[z] * (float)W + ox - 0.5f;
      float y = ry[z] * (float)H + oy - 0.5f;
      float x0f = floorf(x), y0f = floorf(y);
      float lx = x - x0f, ly = y - y0f;
      int x0 = (int)x0f, y0 = (int)y0f;
      int x1 = x0 + 1, y1 = y0 + 1;

      float aw = s_attn[h * 32 + l * 8 + p];
      float w00 = (1.f - ly) * (1.f - lx) * aw;
      float w01 = (1.f - ly) * lx * aw;
      float w10 = ly * (1.f - lx) * aw;
      float w11 = ly * lx * aw;

      bool vx0 = (x0 >= 0) & (x0 < W);
      bool vx1 = (x1 >= 0) & (x1 < W);
      bool vy0 = (y0 >= 0) & (y0 < H);
      bool vy1 = (y1 >= 0) & (y1 < H);
      if (!vx0) w00 = 0.f, w10 = 0.f;
      if (!vx1) w01 = 0.f, w11 = 0.f;
      if (!vy0) w00 = 0.f, w01 = 0.f;
      if (!vy1) w10 = 0.f, w11 = 0.f;

      int x0c = min(max(x0, 0), W - 1);
      int x1c = min(max(x1, 0), W - 1);
      int y0c = min(max(y0, 0), H - 1);
      int y1c = min(max(y1, 0), H - 1);

      float v00 = __bfloat162float(vl[(size_t)(y0c * W + x0c) * 256]);
      float v01 = __bfloat162float(vl[(size_t)(y0c * W + x1c) * 256]);
      float v10 = __bfloat162float(vl[(size_t)(y1c * W + x0c) * 256]);
      float v11 = __bfloat162float(vl[(size_t)(y1c * W + x1c) * 256]);

      acc += w00 * v00 + w01 * v01 + w10 * v10 + w11 * v11;
    }
  }

  out[(size_t)bq * 256 + tid] = acc;
}

extern "C" void kernel_launch(void* const* d_in, const int* in_sizes, int n_in,
                              void* d_out, int out_size, void* d_ws, size_t ws_size,
                              hipStream_t stream) {
  const float* query  = (const float*)d_in[0];
  const float* value  = (const float*)d_in[1];
  const float* refp   = (const float*)d_in[2];
  const float* w_off  = (const float*)d_in[3];
  const float* b_off  = (const float*)d_in[4];
  const float* w_attn = (const float*)d_in[5];
  const float* b_attn = (const float*)d_in[6];
  const float* w_val  = (const float*)d_in[7];
  const float* b_val  = (const float*)d_in[8];
  float* out = (float*)d_out;

  char* ws = (char*)d_ws;
  __hip_bfloat16* vproj = (__hip_bfloat16*)ws;                    // 184950*256*2 = 94,694,400 B
  float* offb  = (float*)(ws + 94694400);                          // 60000*512*4 = 122,880,000 B
  float* attnb = (float*)(ws + 94694400 + 122880000);              // 60000*256*4 =  61,440,000 B
  // total ws use: 279,014,400 B

  const int Mv = BS * NV;  // 184950
  const int Mq = BS * NQ;  // 60000

  gemm_kernel<true><<<dim3((Mv + 15) / 16, 1), 256, 0, stream>>>(value, w_val, b_val, vproj, Mv, 256);
  gemm_kernel<false><<<dim3((Mq + 15) / 16, 2), 256, 0, stream>>>(query, w_off, b_off, offb, Mq, 512);
  gemm_kernel<false><<<dim3((Mq + 15) / 16, 1), 256, 0, stream>>>(query, w_attn, b_attn, attnb, Mq, 256);
  msda_sample_kernel<<<BS * NQ, 256, 0, stream>>>(vproj, offb, attnb, refp, out);
}

// Round 2
// 425.077 us; speedup vs baseline: 3.5418x; 3.5418x over previous
//
#include <hip/hip_runtime.h>
#include <hip/hip_bf16.h>

#define NQ 10000
#define BS 6
#define NV 30825   // 23200 + 5800 + 1450 + 375

typedef __attribute__((ext_vector_type(8))) short bf16x8;
typedef __attribute__((ext_vector_type(4))) float f32x4;

__device__ __forceinline__ void gload_lds16(const void* g, void* l) {
  __builtin_amdgcn_global_load_lds(
      (const __attribute__((address_space(1))) unsigned int*)g,
      (__attribute__((address_space(3))) unsigned int*)l, 16, 0, 0);
}

__device__ __forceinline__ unsigned short bf_bits(float f) {
  __hip_bfloat16 h = __float2bfloat16(f);
  return *(unsigned short*)&h;
}

// ---------------------------------------------------------------------------
// f32 -> bf16 conversion, 4 elems/thread
// ---------------------------------------------------------------------------
__global__ __launch_bounds__(256) void f32_to_bf16_kernel(
    const float* __restrict__ in, unsigned short* __restrict__ out, int n4) {
  int i = blockIdx.x * 256 + threadIdx.x;
  if (i >= n4) return;
  float4 v = ((const float4*)in)[i];
  ushort4 o;
  o.x = bf_bits(v.x); o.y = bf_bits(v.y); o.z = bf_bits(v.z); o.w = bf_bits(v.w);
  ((ushort4*)out)[i] = o;
}

// ---------------------------------------------------------------------------
// Pack + transpose weights to bf16:
//   wvalT [256][256]  = w_val^T
//   wpackT[768][256]  = concat(w_off, w_attn)^T
//   bpack [768]       = concat(b_off, b_attn)
// ---------------------------------------------------------------------------
__global__ __launch_bounds__(256) void prep_weights_kernel(
    const float* __restrict__ w_val, const float* __restrict__ w_off,
    const float* __restrict__ w_attn, const float* __restrict__ b_off,
    const float* __restrict__ b_attn, unsigned short* __restrict__ wvalT,
    unsigned short* __restrict__ wpackT, float* __restrict__ bpack) {
  int i = blockIdx.x * 256 + threadIdx.x;
  if (i < 65536) {
    int n = i >> 8, k = i & 255;
    wvalT[i] = bf_bits(w_val[k * 256 + n]);
  } else if (i < 65536 + 196608) {
    int j = i - 65536;
    int n = j >> 8, k = j & 255;
    float v = (n < 512) ? w_off[k * 512 + n] : w_attn[k * 256 + (n - 512)];
    wpackT[j] = bf_bits(v);
  } else if (i < 65536 + 196608 + 768) {
    int j = i - 262144;
    bpack[j] = (j < 512) ? b_off[j] : b_attn[j - 512];
  }
}

// ---------------------------------------------------------------------------
// MFMA GEMM: C[M,N](bf16) = A[M,256](bf16) @ WT[N,256]^T(bf16) + bias[N](f32)
// 128x128 tile, BK=64, 4 waves (2x2 of 64x64), global_load_lds width 16.
// Requires N % 128 == 0.
// ---------------------------------------------------------------------------
__global__ __launch_bounds__(256) void gemm_mfma_kernel(
    const unsigned short* __restrict__ A, const unsigned short* __restrict__ WT,
    const float* __restrict__ bias, unsigned short* __restrict__ C, int M, int N) {
  __shared__ short As[128 * 64];  // [row][k] 128B rows
  __shared__ short Bs[128 * 64];  // [col][k] 128B rows (WT layout)
  const int tid = threadIdx.x;
  const int wv = tid >> 6;
  const int lane = tid & 63;
  const int wr = wv >> 1, wc = wv & 1;
  const int m0 = blockIdx.x * 128;
  const int n0 = blockIdx.y * 128;

  f32x4 acc[4][4] = {};

  for (int kt = 0; kt < 4; ++kt) {
#pragma unroll
    for (int j = 0; j < 4; ++j) {
      int u = j * 256 + tid;
      int row = u >> 3;
      int kbyte = (u & 7) * 16;
      int ldsoff = (j * 256 + wv * 64) * 16;  // wave-uniform base (bytes)
      // A tile
      int gr = m0 + row; if (gr >= M) gr = M - 1;
      gload_lds16((const char*)A + (size_t)gr * 512 + kt * 128 + kbyte,
                  (char*)As + ldsoff);
      // B tile (WT rows are output cols)
      gload_lds16((const char*)WT + (size_t)(n0 + row) * 512 + kt * 128 + kbyte,
                  (char*)Bs + ldsoff);
    }
    __syncthreads();
#pragma unroll
    for (int kk = 0; kk < 2; ++kk) {
      bf16x8 af[4], bfr[4];
#pragma unroll
      for (int mi = 0; mi < 4; ++mi) {
        int off = (wr * 64 + mi * 16 + (lane & 15)) * 64 + kk * 32 + (lane >> 4) * 8;
        af[mi] = *(const bf16x8*)&As[off];
      }
#pragma unroll
      for (int ni = 0; ni < 4; ++ni) {
        int off = (wc * 64 + ni * 16 + (lane & 15)) * 64 + kk * 32 + (lane >> 4) * 8;
        bfr[ni] = *(const bf16x8*)&Bs[off];
      }
#pragma unroll
      for (int mi = 0; mi < 4; ++mi)
#pragma unroll
        for (int ni = 0; ni < 4; ++ni)
          acc[mi][ni] = __builtin_amdgcn_mfma_f32_16x16x32_bf16(
              af[mi], bfr[ni], acc[mi][ni], 0, 0, 0);
    }
    __syncthreads();
  }

  const int colb = n0 + wc * 64 + (lane & 15);
  float bvn[4];
#pragma unroll
  for (int ni = 0; ni < 4; ++ni) bvn[ni] = bias[colb + ni * 16];
#pragma unroll
  for (int mi = 0; mi < 4; ++mi) {
#pragma unroll
    for (int r = 0; r < 4; ++r) {
      int row = m0 + wr * 64 + mi * 16 + (lane >> 4) * 4 + r;
      if (row < M) {
#pragma unroll
        for (int ni = 0; ni < 4; ++ni)
          C[(size_t)row * N + colb + ni * 16] = bf_bits(acc[mi][ni][r] + bvn[ni]);
      }
    }
  }
}

// ---------------------------------------------------------------------------
// Sampling kernel, phase-split:
//  phase 1: 256 threads = 256 (head,level,point) samples; softmax + bilinear
//           setup once per sample -> LDS (idx,weight) x 4 corners.
//  phase 2: 256 threads = 8 heads x 16 lanes x 2 half-point-sets; each lane
//           gathers bf162 (2 channels) for 16 samples x 4 corners.
// ---------------------------------------------------------------------------
__global__ __launch_bounds__(256) void msda_sample_kernel(
    const __hip_bfloat16* __restrict__ vproj,  // [BS*NV, 256]
    const __hip_bfloat16* __restrict__ C2,     // [BS*NQ, 768]: 512 off | 256 attn
    const float* __restrict__ ref,             // [BS*NQ, 4, 2]
    float* __restrict__ out) {                 // [BS*NQ, 256]
  const int bq = blockIdx.x;
  const int b = bq / NQ;
  const int tid = threadIdx.x;

  __shared__ float2 s_iw[256][4];  // [.x = idx bits, .y = weight]

  {  // ---- phase 1 ----
    const int lp = tid & 31;
    const int l = lp >> 3, p = lp & 7, z = p & 3;
    const __hip_bfloat162* offp = (const __hip_bfloat162*)(C2 + (size_t)bq * 768);
    __hip_bfloat162 ob = offp[tid];
    float ox = __bfloat162float(ob.x), oy = __bfloat162float(ob.y);
    float logit = __bfloat162float(C2[(size_t)bq * 768 + 512 + tid]);

    float mx = logit;
#pragma unroll
    for (int m = 16; m >= 1; m >>= 1) mx = fmaxf(mx, __shfl_xor(mx, m, 32));
    float e = __expf(logit - mx);
    float s = e;
#pragma unroll
    for (int m = 16; m >= 1; m >>= 1) s += __shfl_xor(s, m, 32);
    float aw = e / s;

    float2 rz = *(const float2*)(ref + (size_t)bq * 8 + z * 2);
    const int W = 200 >> l;
    const int H = (l == 3) ? 15 : (116 >> l);
    const int base = (l == 0) ? 0 : (l == 1) ? 23200 : (l == 2) ? 29000 : 30450;

    float x = rz.x * (float)W + ox - 0.5f;
    float y = rz.y * (float)H + oy - 0.5f;
    float x0f = floorf(x), y0f = floorf(y);
    float lx = x - x0f, ly = y - y0f;
    int x0 = (int)x0f, y0 = (int)y0f;
    int x1 = x0 + 1, y1 = y0 + 1;

    float w00 = (1.f - ly) * (1.f - lx) * aw;
    float w01 = (1.f - ly) * lx * aw;
    float w10 = ly * (1.f - lx) * aw;
    float w11 = ly * lx * aw;

    if (!((x0 >= 0) & (x0 < W))) { w00 = 0.f; w10 = 0.f; }
    if (!((x1 >= 0) & (x1 < W))) { w01 = 0.f; w11 = 0.f; }
    if (!((y0 >= 0) & (y0 < H))) { w00 = 0.f; w01 = 0.f; }
    if (!((y1 >= 0) & (y1 < H))) { w10 = 0.f; w11 = 0.f; }

    int x0c = min(max(x0, 0), W - 1);
    int x1c = min(max(x1, 0), W - 1);
    int y0c = min(max(y0, 0), H - 1);
    int y1c = min(max(y1, 0), H - 1);

    s_iw[tid][0] = make_float2(__int_as_float(base + y0c * W + x0c), w00);
    s_iw[tid][1] = make_float2(__int_as_float(base + y0c * W + x1c), w01);
    s_iw[tid][2] = make_float2(__int_as_float(base + y1c * W + x0c), w10);
    s_iw[tid][3] = make_float2(__int_as_float(base + y1c * W + x1c), w11);
  }
  __syncthreads();

  // ---- phase 2 ----
  const int h = tid >> 5;
  const int half = (tid >> 4) & 1;
  const int lane16 = tid & 15;
  const __hip_bfloat162* vb =
      (const __hip_bfloat162*)(vproj + (size_t)b * NV * 256 + h * 32 + lane16 * 2);
  float accx = 0.f, accy = 0.f;
  const int sbase = h * 32 + half * 16;
#pragma unroll 4
  for (int s = 0; s < 16; ++s) {
    int si = sbase + s;
#pragma unroll
    for (int corner = 0; corner < 4; ++corner) {
      float2 iw = s_iw[si][corner];
      int row = __float_as_int(iw.x);
      float w = iw.y;
      __hip_bfloat162 v = vb[(size_t)row * 128];
      accx = fmaf(w, __bfloat162float(v.x), accx);
      accy = fmaf(w, __bfloat162float(v.y), accy);
    }
  }
  accx += __shfl_xor(accx, 16);
  accy += __shfl_xor(accy, 16);
  if (!half) {
    *(float2*)(out + (size_t)bq * 256 + h * 32 + lane16 * 2) = make_float2(accx, accy);
  }
}

extern "C" void kernel_launch(void* const* d_in, const int* in_sizes, int n_in,
                              void* d_out, int out_size, void* d_ws, size_t ws_size,
                              hipStream_t stream) {
  const float* query  = (const float*)d_in[0];
  const float* value  = (const float*)d_in[1];
  const float* refp   = (const float*)d_in[2];
  const float* w_off  = (const float*)d_in[3];
  const float* b_off  = (const float*)d_in[4];
  const float* w_attn = (const float*)d_in[5];
  const float* b_attn = (const float*)d_in[6];
  const float* w_val  = (const float*)d_in[7];
  const float* b_val  = (const float*)d_in[8];
  float* out = (float*)d_out;

  char* ws = (char*)d_ws;
  // layout (bytes):
  //   vproj  bf16 [184950*256]            @ 0          (94,694,400)
  //   valb   bf16 [184950*256]            @ 94,694,400 (94,694,400)  -- dead after gemm_val
  //   C2     bf16 [60000*768]             @ 94,694,400 (92,160,000)  -- aliases valb
  //   qb     bf16 [60000*256]             @ 189,388,800 (30,720,000)
  //   wvalT  bf16 [256*256]               @ 220,108,800 (131,072)
  //   wpackT bf16 [768*256]               @ 220,239,872 (393,216)
  //   bpack  f32  [768]                   @ 220,633,088 (3,072)
  unsigned short* vproj  = (unsigned short*)(ws);
  unsigned short* valb   = (unsigned short*)(ws + 94694400);
  unsigned short* C2     = (unsigned short*)(ws + 94694400);
  unsigned short* qb     = (unsigned short*)(ws + 189388800);
  unsigned short* wvalT  = (unsigned short*)(ws + 220108800);
  unsigned short* wpackT = (unsigned short*)(ws + 220239872);
  float*          bpack  = (float*)        (ws + 220633088);

  const int Mv = BS * NV;  // 184950
  const int Mq = BS * NQ;  // 60000

  prep_weights_kernel<<<1032, 256, 0, stream>>>(w_val, w_off, w_attn, b_off, b_attn,
                                                wvalT, wpackT, bpack);
  f32_to_bf16_kernel<<<(Mv * 64 + 255) / 256, 256, 0, stream>>>(value, valb, Mv * 64);
  f32_to_bf16_kernel<<<(Mq * 64 + 255) / 256, 256, 0, stream>>>(query, qb, Mq * 64);
  gemm_mfma_kernel<<<dim3((Mv + 127) / 128, 2), 256, 0, stream>>>(
      valb, wvalT, b_val, vproj, Mv, 256);
  gemm_mfma_kernel<<<dim3((Mq + 127) / 128, 6), 256, 0, stream>>>(
      qb, wpackT, bpack, C2, Mq, 768);
  msda_sample_kernel<<<BS * NQ, 256, 0, stream>>>(
      (const __hip_bfloat16*)vproj, (const __hip_bfloat16*)C2, refp, out);
}